// Round 3
// baseline (132.968 us; speedup 1.0000x reference)
//
#include <hip/hip_runtime.h>

#define NEGV -1e30f

// Problem constants (fixed by setup_inputs)
constexpr int Bn = 8, Ci = 64, Hn = 64, Wn = 64, Co = 64;

// Tiling: lane = col (64), each thread computes 2 output rows x 4 co.
// Block = 256 thr = 4 waves; wave = 2 rows; block covers 8 rows, 4 co.
// Grid = 16 cog x 8 hg x 8 b = 1024 blocks = 4 blocks/CU = 4 waves/SIMD.
// 12 window loads feed 2px x 4co = 112 useful VALU (vs 9 loads per 112 in R2):
// halves TA/L1 pressure per useful instr -> back to VALU-bound.
constexpr int COB = 4;
constexpr int RPT = 2;

__global__ __launch_bounds__(256, 4)
void maxconv_kernel(const float* __restrict__ x, const float* __restrict__ wt,
                    float* __restrict__ out) {
    const int bid  = blockIdx.x;
    // XCD swizzle: bid%8 == b -> all blocks of batch b on one XCD; its L2
    // holds the 1 MB x[b] plane across all 16 co-groups (cuts HBM re-fetch).
    const int b    = bid & 7;
    const int hg   = (bid >> 3) & 7;
    const int cog  = bid >> 6;                 // 0..15
    const int lane = threadIdx.x & 63;
    const int wv   = threadIdx.x >> 6;         // 0..3
    const int h0   = hg * 8 + wv * 2;          // wave-uniform first output row
    const int co0  = cog * COB;

    const int  cl = lane > 0      ? lane - 1 : 0;       // clamped col offsets
    const int  cr = lane < Wn - 1 ? lane + 1 : Wn - 1;
    const bool eL = (lane == 0), eR = (lane == Wn - 1);
    const bool hasUp = (h0 > 0);          // wave-uniform: row h0-1 exists
    const bool hasDn = (h0 + 2 < Hn);     // wave-uniform: row h0+2 exists

    const float* pc = x + (((size_t)b * Ci) * Hn + h0) * Wn + lane;
    const float* pl = pc + (cl - lane);
    const float* pr = pc + (cr - lane);

    // window rows h0-1 .. h0+2 (rel idx 0..3) x cols {l,c,r}
    float cur[4][3], nxt[4][3];

    auto fetch = [&](const float* c, const float* l, const float* r, float w[4][3]) {
        if (hasUp) { w[0][0] = l[-Wn];    w[0][1] = c[-Wn];    w[0][2] = r[-Wn]; }
        else       { w[0][0] = NEGV;      w[0][1] = NEGV;      w[0][2] = NEGV; }
        w[1][0] = l[0];      w[1][1] = c[0];      w[1][2] = r[0];
        w[2][0] = l[Wn];     w[2][1] = c[Wn];     w[2][2] = r[Wn];
        if (hasDn) { w[3][0] = l[2 * Wn]; w[3][1] = c[2 * Wn]; w[3][2] = r[2 * Wn]; }
        else       { w[3][0] = NEGV;      w[3][1] = NEGV;      w[3][2] = NEGV; }
        if (eL) { w[0][0] = NEGV; w[1][0] = NEGV; w[2][0] = NEGV; w[3][0] = NEGV; }
        if (eR) { w[0][2] = NEGV; w[1][2] = NEGV; w[2][2] = NEGV; w[3][2] = NEGV; }
    };

    float acc[RPT][COB];
#pragma unroll
    for (int r = 0; r < RPT; r++)
#pragma unroll
        for (int c = 0; c < COB; c++) acc[r][c] = NEGV;

    fetch(pc, pl, pr, cur);

#pragma unroll 2
    for (int ci = 0; ci < Ci; ci++) {
        if (ci + 1 < Ci)  // prefetch next ci's window; loads fly over compute
            fetch(pc + Hn * Wn, pl + Hn * Wn, pr + Hn * Wn, nxt);

#pragma unroll
        for (int c = 0; c < COB; c++) {
            // block-uniform address -> scalar (s_load) weight reads
            const float* wp = wt + ((size_t)(co0 + c) * Ci + ci) * 9;
            float w0 = wp[0], w1 = wp[1], w2 = wp[2];
            float w3 = wp[3], w4 = wp[4], w5 = wp[5];
            float w6 = wp[6], w7 = wp[7], w8 = wp[8];
#pragma unroll
            for (int r = 0; r < RPT; r++) {
                float t0 = cur[r + 0][0] + w0;
                float t1 = cur[r + 0][1] + w1;
                float t2 = cur[r + 0][2] + w2;
                float t3 = cur[r + 1][0] + w3;
                float t4 = cur[r + 1][1] + w4;
                float t5 = cur[r + 1][2] + w5;
                float t6 = cur[r + 2][0] + w6;
                float t7 = cur[r + 2][1] + w7;
                float t8 = cur[r + 2][2] + w8;
                float a = acc[r][c];
                a = fmaxf(a, fmaxf(t0, t1));   // v_max3_f32
                a = fmaxf(a, fmaxf(t2, t3));
                a = fmaxf(a, fmaxf(t4, t5));
                a = fmaxf(a, fmaxf(t6, t7));
                a = fmaxf(a, t8);
                acc[r][c] = a;
            }
        }

        pc += Hn * Wn; pl += Hn * Wn; pr += Hn * Wn;
#pragma unroll
        for (int i = 0; i < 4; i++)
#pragma unroll
            for (int j = 0; j < 3; j++) cur[i][j] = nxt[i][j];  // reg rename
    }

    // store 2 rows x 4 co, lane-coalesced
#pragma unroll
    for (int c = 0; c < COB; c++)
#pragma unroll
        for (int r = 0; r < RPT; r++)
            out[(((size_t)b * Co + co0 + c) * Hn + (h0 + r)) * Wn + lane] = acc[r][c];
}

extern "C" void kernel_launch(void* const* d_in, const int* in_sizes, int n_in,
                              void* d_out, int out_size, void* d_ws, size_t ws_size,
                              hipStream_t stream) {
    const float* x  = (const float*)d_in[0];
    const float* wt = (const float*)d_in[1];
    float* out = (float*)d_out;

    maxconv_kernel<<<dim3(16 * 8 * 8), 256, 0, stream>>>(x, wt, out);
}